// Round 10
// baseline (3258.670 us; speedup 1.0000x reference)
//
#include <hip/hip_runtime.h>
#include <stdint.h>

// ---------------------------------------------------------------------------
// GRU embedder: B=128, T=256, D=128, H=512, L=3, reset_after, then
// Hrep = sigmoid(out @ Wd + bd).
//
// Quad-sharing restructure (vs round-8 2304us baseline):
//  - wg = 512 thr = x-quad (4 waves) + h-quad (4 waves), one (mh,mp) 32-row
//    block, 4 adjacent jc columns (64 h-cols). Weights in VGPRs (proven).
//  - The 4 waves of a quad need the SAME 32KB A-block: cooperative sc0sc1
//    load ONCE into LDS; MFMA frags via conflict-free ds_read_b128.
//    Coherent traffic ~5MB/step (was ~21): kills broadcast amplification.
//  - Producers per dependency group: 8 wg-flags (was 64 wave-flags):
//    attacks the straggler-bound period (max over 8, not 64).
//  - Flags: per-writer monotonic, unique writers, min-semantics via __all
//    (rounds 1-9 proven). 16-slot rings + consumed-flags backpressure.
// ---------------------------------------------------------------------------

typedef short vs8 __attribute__((ext_vector_type(8)));   // 8 x bf16 (4 VGPRs)
typedef float vf4 __attribute__((ext_vector_type(4)));

#define DEVFN __device__ __forceinline__

constexpr int TT = 256, BB = 128;

// flag area (uint indices; groups padded to 32 uints = 128B):
//   FH[g]  @ g*32        g = l*4+mh*2+mp : slot jcq, writer = wg (l,mh,mp,jcq)
//   XPc[g] @ 384 + g*32  slot jcq, writer = x-quad of wg (l,mh,mp,jcq), l>=1
//   DPc[q] @ 768 + q*32  q = mh*2+mp, slot dp&1, writer = dense wg dp
constexpr size_t OFF_FLAGS = 0;         // 4096 B
constexpr size_t OFF_BIAS  = 4096;      // [3][4][512] f32 = 24576
constexpr size_t OFF_WDP   = 28672;     // [32][16][64][8] bf16 = 524288
constexpr size_t OFF_WP0   = 552960;    // [96][20][64][8] = 1966080
constexpr size_t OFF_WP1   = 2519040;   // [96][32][64][8] = 3145728
constexpr size_t OFF_WP2   = 5664768;   // 3145728
constexpr size_t OFF_XBF   = 8810496;   // [256][128][128] bf16 = 8388608
constexpr size_t OFF_R0    = 17199104;  // [16][128][512] bf16 = 2097152
constexpr size_t OFF_R1    = 19296256;  // 2097152
constexpr size_t OFF_R2    = 21393408;  // 2097152
// end 23490560 (~22.4 MB)

DEVFN ushort f2bf(float f) {
  union { float f; uint u; } x; x.f = f;
  uint r = (x.u + 0x7FFFu + ((x.u >> 16) & 1u)) >> 16;
  return (ushort)r;
}
DEVFN vf4 mfma16(vs8 a, vs8 b, vf4 c) {
  return __builtin_amdgcn_mfma_f32_16x16x32_bf16(a, b, c, 0, 0, 0);
}

// device-coherent 16B store
DEVFN void stg16_coh(ushort* p, vs8 v) {
  asm volatile("global_store_dwordx4 %0, %1, off sc0 sc1" :: "v"(p), "v"(v) : "memory");
}

// ---- monotonic flags: explicit device-coherent load/store (round-9) -------
DEVFN uint ldflag_coh(const uint* p) {
  uint v;
  asm volatile("global_load_dword %0, %1, off sc0 sc1\n\ts_waitcnt vmcnt(0)"
               : "=v"(v) : "v"(p) : "memory");
  return v;
}
DEVFN void stflag(uint* p, uint v) {
  asm volatile("global_store_dword %0, %1, off sc0 sc1" :: "v"(p), "v"(v) : "memory");
}
// per-lane address and per-lane need; __all = min-semantics
DEVFN void poll_u(const uint* q, uint need) {
  for (;;) {
    uint v = ldflag_coh(q);
    if (__all((int)(v >= need))) break;
  }
  asm volatile("" ::: "memory");
}

// ---- cooperative quad load: 256 threads stage R=32 rows x RS cols to LDS --
// src row-major (RS ushorts/row); LDS rows padded to 520 ushorts.
template<int NCH, int LOG2CPR, int RS, int SC>
DEVFN void coop_load(const ushort* src, ushort (*A)[520], int qtid) {
  vs8 tmp[NCH];
#pragma unroll
  for (int k = 0; k < NCH; ++k) {
    int c = qtid + (k << 8);
    int row = c >> LOG2CPR, col8 = c & ((1 << LOG2CPR) - 1);
    const ushort* p = src + (size_t)row * RS + col8 * 8;
    if (SC) asm volatile("global_load_dwordx4 %0, %1, off sc0 sc1" : "=v"(tmp[k]) : "v"(p));
    else    asm volatile("global_load_dwordx4 %0, %1, off"          : "=v"(tmp[k]) : "v"(p));
  }
  asm volatile("s_waitcnt vmcnt(0)" ::: "memory");
#pragma unroll
  for (int k = 0; k < NCH; ++k) {
    int c = qtid + (k << 8);
    int row = c >> LOG2CPR, col8 = c & ((1 << LOG2CPR) - 1);
    *(vs8*)&A[row][col8 * 8] = tmp[k];
  }
}

// ---------------------------------------------------------------------------
// prep kernels (proven, unchanged)
// ---------------------------------------------------------------------------
__global__ void pack_weights(
    const float* __restrict__ k0, const float* __restrict__ krest,
    const float* __restrict__ rec, const float* __restrict__ wd,
    ushort* __restrict__ wp0, ushort* __restrict__ wp1, ushort* __restrict__ wp2,
    ushort* __restrict__ wdp) {
  const int bid = blockIdx.x, lane = threadIdx.x;
  if (bid >= 8064) {                         // Wd: 32 tiles x 16 ksteps
    int rel = bid - 8064;
    int tile = rel >> 4, ks = rel & 15;
    int col = tile * 16 + (lane & 15);
    int kb = ks * 32 + (lane >> 4) * 8;
    vs8 o;
#pragma unroll
    for (int i = 0; i < 8; ++i) o[i] = (short)f2bf(wd[(size_t)(kb + i) * 512 + col]);
    *(vs8*)&wdp[((size_t)rel * 64 + lane) * 8] = o;
    return;
  }
  const float* WK; const float* UU; ushort* dst; int KS, DinL, rel;
  if (bid < 1920)      { rel = bid;        WK = k0;                         UU = rec;                          dst = wp0; KS = 20; DinL = 128; }
  else if (bid < 4992) { rel = bid - 1920; WK = krest;                      UU = rec + (size_t)512 * 1536;     dst = wp1; KS = 32; DinL = 512; }
  else                 { rel = bid - 4992; WK = krest + (size_t)512 * 1536; UU = rec + (size_t)2 * 512 * 1536; dst = wp2; KS = 32; DinL = 512; }
  int tile = rel / KS, ks = rel % KS;
  int col = tile * 16 + (lane & 15);
  int kb = ks * 32 + (lane >> 4) * 8;
  vs8 o;
#pragma unroll
  for (int i = 0; i < 8; ++i) {
    int k = kb + i;
    float v = (k < DinL) ? WK[(size_t)k * 1536 + col] : UU[(size_t)(k - DinL) * 1536 + col];
    o[i] = (short)f2bf(v);
  }
  *(vs8*)&dst[((size_t)rel * 64 + lane) * 8] = o;
}

__global__ void pack_x(const float* __restrict__ X, ushort* __restrict__ XBF) {
  int id = blockIdx.x * 256 + threadIdx.x;   // T*B*16
  int oct = id & 15, bt = id >> 4;
  int b = bt & 127, t = bt >> 7;
  const float* src = X + ((size_t)b * TT + t) * 128 + oct * 8;
  vs8 o;
#pragma unroll
  for (int i = 0; i < 8; ++i) o[i] = (short)f2bf(src[i]);
  *(vs8*)&XBF[(size_t)id * 8] = o;
}

__global__ void pack_bias(const float* __restrict__ bsrc, float* __restrict__ bp) {
  int l = blockIdx.x, j = threadIdx.x;
  const float* a = bsrc + (size_t)l * 2 * 1536;
  const float* b = a + 1536;
  bp[l * 2048 + j]        = a[j] + b[j];
  bp[l * 2048 + 512 + j]  = a[512 + j] + b[512 + j];
  bp[l * 2048 + 1024 + j] = a[1024 + j];
  bp[l * 2048 + 1536 + j] = b[1024 + j];
}

// ---------------------------------------------------------------------------
// scan body: wg = (l, mh, mp, jcq). wv0-3 = x-quad, wv4-7 = h-quad.
// ---------------------------------------------------------------------------
template<int KX, bool FIRST, bool LASTL>
DEVFN void scan_body(const ushort* __restrict__ Wp, const float* __restrict__ biasL,
                     const ushort* __restrict__ Xsrc, ushort* __restrict__ ring,
                     uint* __restrict__ flg, int l, int mh, int mp, int jcq,
                     int tid, ushort (*Ah)[520], ushort (*Ax)[520],
                     float (*pacc)[28], ushort (*hT)[16]) {
  const int lane = tid & 63;
  const int wv = tid >> 6;
  const bool xq = (wv < 4);
  const int wjc = wv & 3;
  const int jc = jcq * 4 + wjc;
  const int qtid = tid & 255;
  const int rs = lane >> 4;
  constexpr int KS = KX + 16;
  const int ks0 = xq ? 0 : KX;
  const int NK = xq ? KX : 16;
  const int rowbase = mh * 64 + mp * 32;
  const int g_own = l * 4 + mh * 2 + mp;

  // weight slice -> VGPRs, once
  vs8 w[3][16];
#pragma unroll
  for (int g = 0; g < 3; ++g)
#pragma unroll
    for (int k = 0; k < 16; ++k)
      if (k < NK)
        w[g][k] = *(const vs8*)(Wp + (((size_t)(g * 32 + jc) * KS + ks0 + k) * 64 + lane) * 8);

  const int j = jc * 16 + (lane & 15);
  float bzc = 0.f, brc = 0.f, bih = 0.f, brh = 0.f;
  if (!xq) { bzc = biasL[j]; brc = biasL[512 + j]; bih = biasL[1024 + j]; brh = biasL[1536 + j]; }
  float hst[2][4] = {{0, 0, 0, 0}, {0, 0, 0, 0}};

  for (int t = 0; t < TT; ++t) {
    if (xq) {
      if (!FIRST) {
        poll_u(flg + (size_t)((l - 1) * 4 + mh * 2 + mp) * 32 + (lane & 7), (uint)(t + 1));
        coop_load<8, 6, 512, 1>(Xsrc + ((size_t)(t & 15) * BB + rowbase) * 512, Ax, qtid);
      } else {
        coop_load<2, 4, 128, 0>(Xsrc + ((size_t)t * BB + rowbase) * 128, Ax, qtid);
      }
    } else if (t > 0) {
      // merged poll: lanes 0-7 own-group FH >= t; lanes 8-15 backpressure
      const uint* q; uint need;
      if (lane < 8) { q = flg + (size_t)g_own * 32 + lane; need = (uint)t; }
      else if (lane < 16 && t >= 16) {
        if (!LASTL) { q = flg + 384 + (size_t)((l + 1) * 4 + mh * 2 + mp) * 32 + (lane & 7); need = (uint)(t - 15); }
        else        { q = flg + 768 + (size_t)(mh * 2 + mp) * 32 + (lane & 1); need = (uint)(t - 15); }
      } else { q = flg; need = 0u; }
      poll_u(q, need);
      coop_load<8, 6, 512, 1>(ring + ((size_t)((t - 1) & 15) * BB + rowbase) * 512, Ah, qtid);
    }
    __syncthreads();                                        // bar1: LDS A ready
    if (!FIRST && tid == 0)
      stflag(flg + 384 + (size_t)g_own * 32 + jcq, (uint)(t + 1));   // slot consumed

    if (xq) {
      vf4 ax[2][3] = {};
#pragma unroll
      for (int ks = 0; ks < KX; ++ks) {
        vs8 a0 = *(const vs8*)&Ax[(lane & 15)][ks * 32 + rs * 8];
        vs8 a1 = *(const vs8*)&Ax[16 + (lane & 15)][ks * 32 + rs * 8];
#pragma unroll
        for (int g = 0; g < 3; ++g) {
          ax[0][g] = mfma16(a0, w[g][ks], ax[0][g]);
          ax[1][g] = mfma16(a1, w[g][ks], ax[1][g]);
        }
      }
      float* pd = pacc[wjc * 64 + lane];
#pragma unroll
      for (int m = 0; m < 2; ++m)
#pragma unroll
        for (int g = 0; g < 3; ++g)
          *(vf4*)&pd[(m * 3 + g) * 4] = ax[m][g];
      __syncthreads();                                      // bar2
      __syncthreads();                                      // bar3
    } else {
      vf4 ah[2][3] = {};
      if (t > 0) {
#pragma unroll
        for (int ks = 0; ks < 16; ++ks) {
          vs8 a0 = *(const vs8*)&Ah[(lane & 15)][ks * 32 + rs * 8];
          vs8 a1 = *(const vs8*)&Ah[16 + (lane & 15)][ks * 32 + rs * 8];
#pragma unroll
          for (int g = 0; g < 3; ++g) {
            ah[0][g] = mfma16(a0, w[g][ks], ah[0][g]);
            ah[1][g] = mfma16(a1, w[g][ks], ah[1][g]);
          }
        }
      }
      __syncthreads();                                      // bar2: pacc ready
      const float* ps = pacc[wjc * 64 + lane];
#pragma unroll
      for (int m = 0; m < 2; ++m) {
        vf4 pz = *(const vf4*)&ps[(m * 3 + 0) * 4];
        vf4 pr = *(const vf4*)&ps[(m * 3 + 1) * 4];
        vf4 ph = *(const vf4*)&ps[(m * 3 + 2) * 4];
#pragma unroll
        for (int i = 0; i < 4; ++i) {
          float z = 1.f / (1.f + __expf(-(pz[i] + ah[m][0][i] + bzc)));
          float r = 1.f / (1.f + __expf(-(pr[i] + ah[m][1][i] + brc)));
          float pre = ph[i] + bih + r * (ah[m][2][i] + brh);
          float e = __expf(-2.f * fabsf(pre));
          float th = (1.f - e) / (1.f + e);
          th = (pre < 0.f) ? -th : th;
          float hn = z * hst[m][i] + (1.f - z) * th;
          hst[m][i] = hn;
          hT[wjc * 32 + m * 16 + rs * 4 + i][lane & 15] = f2bf(hn);
        }
      }
      // coalesced publish: one 16B sc0sc1 store per lane (32 rows x 16 cols)
      {
        int hr = lane >> 1, ch = lane & 1;
        ushort* dst = ring + (size_t)(t & 15) * BB * 512
                    + (size_t)(rowbase + hr) * 512 + jc * 16 + ch * 8;
        vs8 v = *(const vs8*)&hT[wjc * 32 + hr][ch * 8];
        stg16_coh(dst, v);
      }
      asm volatile("s_waitcnt vmcnt(0)" ::: "memory");
      __syncthreads();                                      // bar3: stores drained
    }
    if (tid == 0) stflag(flg + (size_t)g_own * 32 + jcq, (uint)(t + 1));  // h(t) published
  }
}

// ---------------------------------------------------------------------------
// dense body: 8 wgs x 512 thr; wv: jh = wv>>2, wsub = wv&3; rows dp*16..+16
// ---------------------------------------------------------------------------
DEVFN void dense_body(const ushort* __restrict__ ring2, uint* __restrict__ flg,
                      const ushort* __restrict__ WdP,
                      const float* __restrict__ bdv, float* __restrict__ dOut,
                      int dp, int tid) {
  const int lane = tid & 63, wv = tid >> 6, rs = lane >> 4;
  const int jh = wv >> 2, wsub = wv & 3;
  const int mhd = dp >> 2;
  const int mpd = (dp >> 1) & 1;
  float bq[4];
#pragma unroll
  for (int u = 0; u < 4; ++u) bq[u] = bdv[(jh * 16 + wsub * 4 + u) * 16 + (lane & 15)];
  for (int t = 0; t < TT; ++t) {
    poll_u(flg + (size_t)(2 * 4 + mhd * 2 + mpd) * 32 + (lane & 7), (uint)(t + 1));
    const ushort* base = ring2 + (size_t)(t & 15) * BB * 512
                       + (size_t)(dp * 16 + (lane & 15)) * 512 + rs * 8;
    vs8 fr[16];
#pragma unroll
    for (int ks = 0; ks < 16; ++ks)
      asm volatile("global_load_dwordx4 %0, %1, off sc0 sc1" : "=v"(fr[ks]) : "v"(base + ks * 32));
    asm volatile("s_waitcnt vmcnt(0)" ::: "memory");
    __builtin_amdgcn_sched_barrier(0);
    __syncthreads();                   // all 8 waves consumed slot t
    if (tid == 0) stflag(flg + 768 + (size_t)(mhd * 2 + mpd) * 32 + (dp & 1), (uint)(t + 1));
    vf4 acc[4] = {{0,0,0,0},{0,0,0,0},{0,0,0,0},{0,0,0,0}};
#pragma unroll
    for (int ks = 0; ks < 16; ++ks)
#pragma unroll
      for (int u = 0; u < 4; ++u) {
        vs8 b = *(const vs8*)&WdP[(((size_t)(jh * 16 + wsub * 4 + u) * 16 + ks) * 64 + lane) * 8];
        acc[u] = mfma16(fr[ks], b, acc[u]);
      }
#pragma unroll
    for (int u = 0; u < 4; ++u) {
      int col = (jh * 16 + wsub * 4 + u) * 16 + (lane & 15);
#pragma unroll
      for (int i = 0; i < 4; ++i) {
        float v = acc[u][i] + bq[u];
        float s = 1.f / (1.f + __expf(-v));
        int b = dp * 16 + rs * 4 + i;
        dOut[((size_t)b * TT + t) * 512 + col] = s;
      }
    }
    __syncthreads();
  }
}

// ---------------------------------------------------------------------------
// fused persistent kernel: 96 scan wgs + 8 dense wgs (all 512 thr)
// ---------------------------------------------------------------------------
__global__ __launch_bounds__(512, 1) void gru_fused(uint8_t* __restrict__ ws,
                                                    const float* __restrict__ bd,
                                                    float* __restrict__ dOut) {
  __shared__ __align__(16) ushort Ah[32][520];    // 33280 B
  __shared__ __align__(16) ushort Ax[32][520];    // 33280 B
  __shared__ __align__(16) float pacc[256][28];   // 28672 B
  __shared__ __align__(16) ushort hT[128][16];    // 4096 B
  const int bid = blockIdx.x;
  const int tid = threadIdx.x;

  uint* flg = (uint*)(ws + OFF_FLAGS);
  const float* bp = (const float*)(ws + OFF_BIAS);
  const ushort* wdp = (const ushort*)(ws + OFF_WDP);
  const ushort* wp0 = (const ushort*)(ws + OFF_WP0);
  const ushort* wp1 = (const ushort*)(ws + OFF_WP1);
  const ushort* wp2 = (const ushort*)(ws + OFF_WP2);
  const ushort* xbf = (const ushort*)(ws + OFF_XBF);
  ushort* r0 = (ushort*)(ws + OFF_R0);
  ushort* r1 = (ushort*)(ws + OFF_R1);
  ushort* r2 = (ushort*)(ws + OFF_R2);

  if (bid < 96) {
    const int l = bid >> 5, rem = bid & 31;
    const int mh = rem >> 4, mp = (rem >> 3) & 1, jcq = rem & 7;
    if (l == 0)
      scan_body<4, true, false>(wp0, bp, xbf, r0, flg, 0, mh, mp, jcq, tid, Ah, Ax, pacc, hT);
    else if (l == 1)
      scan_body<16, false, false>(wp1, bp + 2048, r0, r1, flg, 1, mh, mp, jcq, tid, Ah, Ax, pacc, hT);
    else
      scan_body<16, false, true>(wp2, bp + 4096, r1, r2, flg, 2, mh, mp, jcq, tid, Ah, Ax, pacc, hT);
  } else {
    dense_body(r2, flg, wdp, bd, dOut, bid - 96, tid);
  }
}

// ---------------------------------------------------------------------------
extern "C" void kernel_launch(void* const* d_in, const int* in_sizes, int n_in,
                              void* d_out, int out_size, void* d_ws, size_t ws_size,
                              hipStream_t stream) {
  (void)in_sizes; (void)n_in; (void)out_size; (void)ws_size;
  const float* X     = (const float*)d_in[0];
  const float* k0    = (const float*)d_in[1];
  const float* krest = (const float*)d_in[2];
  const float* rec   = (const float*)d_in[3];
  const float* bsrc  = (const float*)d_in[4];
  const float* wd    = (const float*)d_in[5];
  const float* bd    = (const float*)d_in[6];
  uint8_t* ws = (uint8_t*)d_ws;

  hipMemsetAsync(ws + OFF_FLAGS, 0, 4096, stream);
  pack_weights<<<8576, 64, 0, stream>>>(k0, krest, rec, wd,
      (ushort*)(ws + OFF_WP0), (ushort*)(ws + OFF_WP1), (ushort*)(ws + OFF_WP2),
      (ushort*)(ws + OFF_WDP));
  pack_bias<<<3, 512, 0, stream>>>(bsrc, (float*)(ws + OFF_BIAS));
  pack_x<<<2048, 256, 0, stream>>>(X, (ushort*)(ws + OFF_XBF));

  gru_fused<<<104, 512, 0, stream>>>(ws, bd, (float*)d_out);
}

// Round 13
// 1608.573 us; speedup vs baseline: 2.0258x; 2.0258x over previous
//
#include <hip/hip_runtime.h>
#include <stdint.h>

// ---------------------------------------------------------------------------
// GRU embedder: B=128, T=256, D=128, H=512, L=3, reset_after, then
// Hrep = sigmoid(out @ Wd + bd).
//
// EXACT R8 proven structure (2304us): single fused persistent kernel,
// 192 scan wgs (3 layers x 2 batch-halves x 32 col-chunks) + 16 dense wgs,
// weights in VGPRs, 16-slot rings, per-writer monotonic flags (min-semantics
// via 64-lane __all), coalesced 16B sc0sc1 publish via LDS transpose,
// busy-spin polls, __hip_atomic agent-scope flag ops.
//
// ONE change vs R8: every flag is padded to its own 128B cache line
// (flag k at uint index k*32). Hypothesis: R8's 128 flags on 4 cache lines
// put ~500 concurrent device-scope poll loads on each line; the producer's
// flag STORE queues behind that storm -> queue-bound flag visibility
// (~4us), the structure-invariant ~9us/step period. Padding spreads polls
// over 32 lines (2 lanes each) -> ~8x less per-line concurrency.
// ---------------------------------------------------------------------------

typedef short vs8 __attribute__((ext_vector_type(8)));   // 8 x bf16 (4 VGPRs)
typedef float vf4 __attribute__((ext_vector_type(4)));

#define DEVFN __device__ __forceinline__

constexpr int TT = 256, BB = 128;

// ws layout (bytes). Flag k lives at uint index k*32 (128B line each).
//   fh0: k=0..127 @ [0,4096) uints      fh1: @ [4096,8192)   fh2: @ [8192,12288)
//   dprog: 16 flags @ [12288,12800)     xprogA: 128 @ [12800,16896)
//   xprogB: 128 @ [16896,20992)         -> 83968 B, pad to 86016
constexpr size_t OFF_FLAGS = 0;         // 86016 B
constexpr size_t OFF_BIAS  = 86016;     // [3][4][512] f32 = 24576
constexpr size_t OFF_WDP   = 110592;    // [32][16][64][8] bf16 = 524288
constexpr size_t OFF_WP0   = 634880;    // [96][20][64][8] = 1966080
constexpr size_t OFF_WP1   = 2600960;   // [96][32][64][8] = 3145728
constexpr size_t OFF_WP2   = 5746688;   // 3145728
constexpr size_t OFF_XBF   = 8892416;   // [256][128][128] bf16 = 8388608
constexpr size_t OFF_R0    = 17281024;  // [16][128][512] bf16 = 2097152
constexpr size_t OFF_R1    = 19378176;  // 2097152
constexpr size_t OFF_R2    = 21475328;  // 2097152
// end 23572480 (~22.5 MB)

DEVFN ushort f2bf(float f) {
  union { float f; uint u; } x; x.f = f;
  uint r = (x.u + 0x7FFFu + ((x.u >> 16) & 1u)) >> 16;
  return (ushort)r;
}
DEVFN vf4 mfma16(vs8 a, vs8 b, vf4 c) {
  return __builtin_amdgcn_mfma_f32_16x16x32_bf16(a, b, c, 0, 0, 0);
}

// device-coherent 16B store
DEVFN void stg16_coh(ushort* p, vs8 v) {
  asm volatile("global_store_dwordx4 %0, %1, off sc0 sc1" :: "v"(p), "v"(v) : "memory");
}

// ---- relaxed agent-scope monotonic flags; PADDED to 128B/flag -------------
DEVFN void stflag(uint* p, uint v) {
  __hip_atomic_store(p, v, __ATOMIC_RELAXED, __HIP_MEMORY_SCOPE_AGENT);
}
// flag k of the quadrant at f + k*32; lane polls flag ((lane&31)<<1)|mp
DEVFN void poll32s2(const uint* f, int mp, uint need, int lane) {
  const uint* q = f + ((size_t)((((lane & 31) << 1) | mp)) << 5);
  for (;;) {
    uint v = __hip_atomic_load(q, __ATOMIC_RELAXED, __HIP_MEMORY_SCOPE_AGENT);
    if (__all((int)(v >= need))) break;
  }
  asm volatile("" ::: "memory");
}
DEVFN void poll4(const uint* f, uint need, int lane) {
  for (;;) {
    uint v = need;
    if (lane < 4) v = __hip_atomic_load(f + (size_t)lane * 32, __ATOMIC_RELAXED, __HIP_MEMORY_SCOPE_AGENT);
    if (__all((int)(v >= need))) break;
  }
  asm volatile("" ::: "memory");
}

// issue 2*NKS coherent 16B A-frag loads, one wait, fence the scheduler
template<int NKS>
DEVFN void load_frags_coh(const ushort* base, int row0, int lane,
                          vs8 (&f0)[NKS], vs8 (&f1)[NKS]) {
  const ushort* p0 = base + (size_t)(row0 + (lane & 15)) * 512 + ((lane >> 4) << 3);
  const ushort* p1 = p0 + 16 * 512;
#pragma unroll
  for (int ks = 0; ks < NKS; ++ks) {
    asm volatile("global_load_dwordx4 %0, %1, off sc0 sc1" : "=v"(f0[ks]) : "v"(p0 + ks * 32));
    asm volatile("global_load_dwordx4 %0, %1, off sc0 sc1" : "=v"(f1[ks]) : "v"(p1 + ks * 32));
  }
  asm volatile("s_waitcnt vmcnt(0)" ::: "memory");
  __builtin_amdgcn_sched_barrier(0);
}

// ---------------------------------------------------------------------------
// prep kernels (proven)
// ---------------------------------------------------------------------------
__global__ void pack_weights(
    const float* __restrict__ k0, const float* __restrict__ krest,
    const float* __restrict__ rec, const float* __restrict__ wd,
    ushort* __restrict__ wp0, ushort* __restrict__ wp1, ushort* __restrict__ wp2,
    ushort* __restrict__ wdp) {
  const int bid = blockIdx.x, lane = threadIdx.x;
  if (bid >= 8064) {                         // Wd: 32 tiles x 16 ksteps
    int rel = bid - 8064;
    int tile = rel >> 4, ks = rel & 15;
    int col = tile * 16 + (lane & 15);
    int kb = ks * 32 + (lane >> 4) * 8;
    vs8 o;
#pragma unroll
    for (int i = 0; i < 8; ++i) o[i] = (short)f2bf(wd[(size_t)(kb + i) * 512 + col]);
    *(vs8*)&wdp[((size_t)rel * 64 + lane) * 8] = o;
    return;
  }
  const float* WK; const float* UU; ushort* dst; int KS, DinL, rel;
  if (bid < 1920)      { rel = bid;        WK = k0;                         UU = rec;                          dst = wp0; KS = 20; DinL = 128; }
  else if (bid < 4992) { rel = bid - 1920; WK = krest;                      UU = rec + (size_t)512 * 1536;     dst = wp1; KS = 32; DinL = 512; }
  else                 { rel = bid - 4992; WK = krest + (size_t)512 * 1536; UU = rec + (size_t)2 * 512 * 1536; dst = wp2; KS = 32; DinL = 512; }
  int tile = rel / KS, ks = rel % KS;
  int col = tile * 16 + (lane & 15);
  int kb = ks * 32 + (lane >> 4) * 8;
  vs8 o;
#pragma unroll
  for (int i = 0; i < 8; ++i) {
    int k = kb + i;
    float v = (k < DinL) ? WK[(size_t)k * 1536 + col] : UU[(size_t)(k - DinL) * 1536 + col];
    o[i] = (short)f2bf(v);
  }
  *(vs8*)&dst[((size_t)rel * 64 + lane) * 8] = o;
}

__global__ void pack_x(const float* __restrict__ X, ushort* __restrict__ XBF) {
  int id = blockIdx.x * 256 + threadIdx.x;   // T*B*16
  int oct = id & 15, bt = id >> 4;
  int b = bt & 127, t = bt >> 7;
  const float* src = X + ((size_t)b * TT + t) * 128 + oct * 8;
  vs8 o;
#pragma unroll
  for (int i = 0; i < 8; ++i) o[i] = (short)f2bf(src[i]);
  *(vs8*)&XBF[(size_t)id * 8] = o;
}

__global__ void pack_bias(const float* __restrict__ bsrc, float* __restrict__ bp) {
  int l = blockIdx.x, j = threadIdx.x;
  const float* a = bsrc + (size_t)l * 2 * 1536;
  const float* b = a + 1536;
  bp[l * 2048 + j]        = a[j] + b[j];
  bp[l * 2048 + 512 + j]  = a[512 + j] + b[512 + j];
  bp[l * 2048 + 1024 + j] = a[1024 + j];
  bp[l * 2048 + 1536 + j] = b[1024 + j];
}

// ---------------------------------------------------------------------------
// scan body: one (layer, mh, jc) wg. wv0,1 = x-waves, wv2,3 = h-waves.
// ---------------------------------------------------------------------------
template<int KX, bool FIRST, bool LASTL>
DEVFN void scan_body(const ushort* __restrict__ Wp, const float* __restrict__ biasL,
                     const ushort* __restrict__ Xsrc, ushort* __restrict__ ring,
                     uint* fh_self, const uint* fh_prev,
                     uint* xprog_self, const uint* bpf,
                     int mh, int jc, int tid,
                     float* pacc, ushort* hT) {
  const int lane = tid & 63;
  const int wv = tid >> 6;
  const int rs = lane >> 4;
  const int mp = wv & 1;
  const bool xw = (wv < 2);
  const int rowA = mh * 64 + mp * 32;
  constexpr int KS = KX + 16;
  const int ks0 = xw ? 0 : KX;
  const int NK = xw ? KX : 16;

  // weight slice -> VGPRs, once
  vs8 w[3][16];
#pragma unroll
  for (int g = 0; g < 3; ++g)
#pragma unroll
    for (int k = 0; k < 16; ++k)
      if (k < NK)
        w[g][k] = *(const vs8*)(Wp + (((size_t)(g * 32 + jc) * KS + ks0 + k) * 64 + lane) * 8);

  const int j = jc * 16 + (lane & 15);
  float bzc = 0.f, brc = 0.f, bih = 0.f, brh = 0.f;
  if (!xw) { bzc = biasL[j]; brc = biasL[512 + j]; bih = biasL[1024 + j]; brh = biasL[1536 + j]; }
  float hst[2][4] = {{0, 0, 0, 0}, {0, 0, 0, 0}};

  for (int t = 0; t < TT; ++t) {
    if (xw) {
      // ---- x-projection wave: x(t) @ Wk -> pacc ----
      vf4 ax[2][3] = {};
      if (FIRST) {
        const ushort* xb = Xsrc + (size_t)t * BB * 128;
        const ushort* q0 = xb + (size_t)(rowA + (lane & 15)) * 128 + ((lane >> 4) << 3);
        const ushort* q1 = q0 + (size_t)16 * 128;
#pragma unroll
        for (int ks = 0; ks < KX; ++ks) {
          vs8 a0 = *(const vs8*)(q0 + ks * 32);
          vs8 a1 = *(const vs8*)(q1 + ks * 32);
#pragma unroll
          for (int g = 0; g < 3; ++g) {
            ax[0][g] = mfma16(a0, w[g][ks], ax[0][g]);
            ax[1][g] = mfma16(a1, w[g][ks], ax[1][g]);
          }
        }
      } else {
        // wait for prev layer's h(t) rows of this (mh, mp) block
        poll32s2(fh_prev + (size_t)mh * 64 * 32, mp, (uint)(t + 1), lane);
        const ushort* xb = Xsrc + (size_t)(t & 15) * BB * 512;
        vs8 f0[16], f1[16];
        load_frags_coh<16>(xb, rowA, lane, f0, f1);
        if (lane == 0) stflag(xprog_self + (size_t)(mh * 64 + jc * 2 + mp) * 32, (uint)(t + 1));
#pragma unroll
        for (int ks = 0; ks < 16; ++ks)
#pragma unroll
          for (int g = 0; g < 3; ++g) {
            ax[0][g] = mfma16(f0[ks], w[g][ks], ax[0][g]);
            ax[1][g] = mfma16(f1[ks], w[g][ks], ax[1][g]);
          }
      }
      float* pd = &pacc[(((size_t)(t & 1) * 2 + mp) * 64 + lane) * 24];
#pragma unroll
      for (int m = 0; m < 2; ++m)
#pragma unroll
        for (int g = 0; g < 3; ++g)
          *(vf4*)&pd[(m * 3 + g) * 4] = ax[m][g];
      __syncthreads();
    } else {
      // ---- recurrence wave: h(t-1) @ U -> gates -> publish h(t) ----
      vf4 ah[2][3] = {};
      if (t > 0) {
        poll32s2(fh_self + (size_t)mh * 64 * 32, mp, (uint)t, lane);  // peers' h(t-1)
        const ushort* hsrc = ring + (size_t)((t - 1) & 15) * BB * 512;
        vs8 f0[16], f1[16];
        load_frags_coh<16>(hsrc, rowA, lane, f0, f1);
#pragma unroll
        for (int ks = 0; ks < 16; ++ks)
#pragma unroll
          for (int g = 0; g < 3; ++g) {
            ah[0][g] = mfma16(f0[ks], w[g][ks], ah[0][g]);
            ah[1][g] = mfma16(f1[ks], w[g][ks], ah[1][g]);
          }
      }
      __syncthreads();
      // combine with x partials, gate math
      const float* ps = &pacc[(((size_t)(t & 1) * 2 + mp) * 64 + lane) * 24];
#pragma unroll
      for (int m = 0; m < 2; ++m) {
        vf4 pz = *(const vf4*)&ps[(m * 3 + 0) * 4];
        vf4 pr = *(const vf4*)&ps[(m * 3 + 1) * 4];
        vf4 ph = *(const vf4*)&ps[(m * 3 + 2) * 4];
#pragma unroll
        for (int i = 0; i < 4; ++i) {
          float z = 1.f / (1.f + __expf(-(pz[i] + ah[m][0][i] + bzc)));
          float r = 1.f / (1.f + __expf(-(pr[i] + ah[m][1][i] + brc)));
          float pre = ph[i] + bih + r * (ah[m][2][i] + brh);
          float e = __expf(-2.f * fabsf(pre));
          float th = (1.f - e) / (1.f + e);
          th = (pre < 0.f) ? -th : th;
          float hn = z * hst[m][i] + (1.f - z) * th;
          hst[m][i] = hn;
          hT[(size_t)(mp * 32 + m * 16 + rs * 4 + i) * 16 + (lane & 15)] = f2bf(hn);
        }
      }
      // backpressure before overwriting ring slot t&15 (held step t-16)
      if (t >= 16) {
        if (LASTL) poll4(bpf + (size_t)((mh * 4 + mp * 2) * 2) * 32, (uint)(t - 15), lane);
        else       poll32s2(bpf + (size_t)mh * 64 * 32, mp, (uint)(t - 15), lane);
      }
      // coalesced publish: one 16B sc0sc1 store per lane
      const int flat = mp * 64 + lane;          // 0..127 over the two h-waves
      const int hr = flat >> 1, ch = flat & 1;  // hr in own wave's 32-row block
      ushort* dst = ring + (size_t)(t & 15) * BB * 512
                  + (size_t)(mh * 64 + hr) * 512 + jc * 16 + ch * 8;
      vs8 v = *(const vs8*)&hT[(size_t)hr * 16 + ch * 8];
      stg16_coh(dst, v);
      asm volatile("s_waitcnt vmcnt(0)" ::: "memory");
      if (lane == 0) stflag(fh_self + (size_t)(mh * 64 + jc * 2 + mp) * 32, (uint)(t + 1));
    }
  }
}

// ---------------------------------------------------------------------------
// dense body (proven, 16-slot ring)
// ---------------------------------------------------------------------------
DEVFN void dense_body(const ushort* __restrict__ ring2, const uint* fh2,
                      uint* dprog, const ushort* __restrict__ WdP,
                      const float* __restrict__ bdv, float* __restrict__ dOut,
                      int rel, int tid) {
  const int lane = tid & 63, wv = tid >> 6, rs = lane >> 4;
  const int dp = rel >> 1, jh = rel & 1;
  const int mhd = dp >> 2;
  const int mpd = (dp >> 1) & 1;
  float bq[4];
#pragma unroll
  for (int u = 0; u < 4; ++u) bq[u] = bdv[(jh * 16 + wv * 4 + u) * 16 + (lane & 15)];
  for (int t = 0; t < TT; ++t) {
    poll32s2(fh2 + (size_t)mhd * 64 * 32, mpd, (uint)(t + 1), lane);
    const ushort* base = ring2 + (size_t)(t & 15) * BB * 512
                       + (size_t)(dp * 16 + (lane & 15)) * 512 + ((lane >> 4) << 3);
    vs8 fr[16];
#pragma unroll
    for (int ks = 0; ks < 16; ++ks)
      asm volatile("global_load_dwordx4 %0, %1, off sc0 sc1" : "=v"(fr[ks]) : "v"(base + ks * 32));
    asm volatile("s_waitcnt vmcnt(0)" ::: "memory");
    __builtin_amdgcn_sched_barrier(0);
    __syncthreads();                   // all 4 waves consumed slot t
    if (tid == 0) stflag(dprog + (size_t)rel * 32, (uint)(t + 1));
    vf4 acc[4] = {{0,0,0,0},{0,0,0,0},{0,0,0,0},{0,0,0,0}};
#pragma unroll
    for (int ks = 0; ks < 16; ++ks)
#pragma unroll
      for (int u = 0; u < 4; ++u) {
        vs8 b = *(const vs8*)&WdP[(((size_t)(jh * 16 + wv * 4 + u) * 16 + ks) * 64 + lane) * 8];
        acc[u] = mfma16(fr[ks], b, acc[u]);
      }
#pragma unroll
    for (int u = 0; u < 4; ++u) {
      int col = (jh * 16 + wv * 4 + u) * 16 + (lane & 15);
#pragma unroll
      for (int i = 0; i < 4; ++i) {
        float v = acc[u][i] + bq[u];
        float s = 1.f / (1.f + __expf(-v));
        int b = dp * 16 + rs * 4 + i;
        dOut[((size_t)b * TT + t) * 512 + col] = s;
      }
    }
    __syncthreads();
  }
}

// ---------------------------------------------------------------------------
// fused persistent kernel: 192 scan wgs + 16 dense wgs
// ---------------------------------------------------------------------------
__global__ __launch_bounds__(256, 1) void gru_fused(uint8_t* __restrict__ ws,
                                                    const float* __restrict__ bd,
                                                    float* __restrict__ dOut) {
  __shared__ __align__(16) float pacc[2 * 2 * 64 * 24];   // 24 KB
  __shared__ __align__(16) ushort hT[64 * 16];            // 2 KB
  const int bid = blockIdx.x;
  const int tid = threadIdx.x;

  uint* flags = (uint*)(ws + OFF_FLAGS);
  uint* fh0 = flags;                       // 128 flags @ *32
  uint* fh1 = flags + 4096;
  uint* fh2 = flags + 8192;
  uint* dprog = flags + 12288;             // 16 flags @ *32
  uint* xprogA = flags + 12800;            // 128 flags @ *32
  uint* xprogB = flags + 16896;
  const float* bp = (const float*)(ws + OFF_BIAS);
  const ushort* wdp = (const ushort*)(ws + OFF_WDP);
  const ushort* wp0 = (const ushort*)(ws + OFF_WP0);
  const ushort* wp1 = (const ushort*)(ws + OFF_WP1);
  const ushort* wp2 = (const ushort*)(ws + OFF_WP2);
  const ushort* xbf = (const ushort*)(ws + OFF_XBF);
  ushort* r0 = (ushort*)(ws + OFF_R0);
  ushort* r1 = (ushort*)(ws + OFF_R1);
  ushort* r2 = (ushort*)(ws + OFF_R2);

  if (bid < 192) {
    const int l = bid >> 6, rem = bid & 63;
    const int mh = rem >> 5, jc = rem & 31;
    if (l == 0)
      scan_body<4, true, false>(wp0, bp, xbf, r0, fh0, nullptr, nullptr, xprogA,
                                mh, jc, tid, pacc, hT);
    else if (l == 1)
      scan_body<16, false, false>(wp1, bp + 2048, r0, r1, fh1, fh0, xprogA, xprogB,
                                  mh, jc, tid, pacc, hT);
    else
      scan_body<16, false, true>(wp2, bp + 4096, r1, r2, fh2, fh1, xprogB, dprog,
                                 mh, jc, tid, pacc, hT);
  } else {
    dense_body(r2, fh2, dprog, wdp, bd, dOut, bid - 192, tid);
  }
}

// ---------------------------------------------------------------------------
extern "C" void kernel_launch(void* const* d_in, const int* in_sizes, int n_in,
                              void* d_out, int out_size, void* d_ws, size_t ws_size,
                              hipStream_t stream) {
  (void)in_sizes; (void)n_in; (void)out_size; (void)ws_size;
  const float* X     = (const float*)d_in[0];
  const float* k0    = (const float*)d_in[1];
  const float* krest = (const float*)d_in[2];
  const float* rec   = (const float*)d_in[3];
  const float* bsrc  = (const float*)d_in[4];
  const float* wd    = (const float*)d_in[5];
  const float* bd    = (const float*)d_in[6];
  uint8_t* ws = (uint8_t*)d_ws;

  hipMemsetAsync(ws + OFF_FLAGS, 0, 86016, stream);
  pack_weights<<<8576, 64, 0, stream>>>(k0, krest, rec, wd,
      (ushort*)(ws + OFF_WP0), (ushort*)(ws + OFF_WP1), (ushort*)(ws + OFF_WP2),
      (ushort*)(ws + OFF_WDP));
  pack_bias<<<3, 512, 0, stream>>>(bsrc, (float*)(ws + OFF_BIAS));
  pack_x<<<2048, 256, 0, stream>>>(X, (ushort*)(ws + OFF_XBF));

  gru_fused<<<208, 256, 0, stream>>>(ws, bd, (float*)d_out);
}